// Round 1
// baseline (100.457 us; speedup 1.0000x reference)
//
#include <hip/hip_runtime.h>
#include <math.h>

#define MAXC 1024
#define NMS_T 0.3f

// One block per (image, class>=1) task.
__global__ __launch_bounds__(256) void nms_class_kernel(
    const float* __restrict__ cls_prob, const float* __restrict__ rois,
    const float* __restrict__ bbox_pred, const float* __restrict__ im_info,
    const float* __restrict__ thr, float* __restrict__ ws_boxes,
    int* __restrict__ ws_counts, int B, int R, int C)
{
    const int task = blockIdx.x;
    const int NC = C - 1;
    const int b = task / NC;
    const int c = 1 + (task % NC);
    const int tid = threadIdx.x;

    __shared__ int s_cnt;
    __shared__ float s_sc[MAXC];     // compacted scores (unsorted)
    __shared__ int   s_ri[MAXC];     // compacted roi indices
    __shared__ float s_bx[MAXC][4];  // boxes in SORTED order
    __shared__ float s_area[MAXC];   // areas in sorted order
    __shared__ int   s_keep[MAXC];

    if (tid == 0) s_cnt = 0;
    __syncthreads();

    // Phase A: compact valid candidates (score > per-class threshold)
    const float tc = thr[c];
    for (int r = tid; r < R; r += blockDim.x) {
        float s = cls_prob[((size_t)b * R + r) * C + c];
        if (s > tc) {
            int p = atomicAdd(&s_cnt, 1);
            if (p < MAXC) { s_sc[p] = s; s_ri[p] = r; }
        }
    }
    __syncthreads();
    int K = s_cnt; if (K > MAXC) K = MAXC;

    const float maxx = im_info[b * 3 + 1] - 1.0f;
    const float maxy = im_info[b * 3 + 0] - 1.0f;

    // Phase B: rank by (score desc, roi idx asc) == stable argsort(-s);
    // decode + clip box directly into its sorted slot.
    for (int i = tid; i < K; i += blockDim.x) {
        const float si = s_sc[i];
        const int   ri = s_ri[i];
        int rank = 0;
        for (int j = 0; j < K; j++) {
            float sj = s_sc[j];
            rank += (sj > si) || (sj == si && s_ri[j] < ri);
        }
        const float* rp = rois + ((size_t)b * R + ri) * 5;
        float rx1 = rp[1], ry1 = rp[2], rx2 = rp[3], ry2 = rp[4];
        float w  = rx2 - rx1 + 1.0f;
        float h  = ry2 - ry1 + 1.0f;
        float cx = rx1 + 0.5f * w;
        float cy = ry1 + 0.5f * h;
        const float* dp = bbox_pred + (((size_t)b * R + ri) * C + c) * 4;
        float d0 = dp[0] * 0.1f, d1 = dp[1] * 0.1f;
        float d2 = dp[2] * 0.2f, d3 = dp[3] * 0.2f;
        float pcx = d0 * w + cx;
        float pcy = d1 * h + cy;
        float pw  = expf(d2) * w;
        float ph  = expf(d3) * h;
        float x1 = fminf(fmaxf(pcx - 0.5f * pw, 0.0f), maxx);
        float x2 = fminf(fmaxf(pcx + 0.5f * pw, 0.0f), maxx);
        float y1 = fminf(fmaxf(pcy - 0.5f * ph, 0.0f), maxy);
        float y2 = fminf(fmaxf(pcy + 0.5f * ph, 0.0f), maxy);
        s_bx[rank][0] = x1; s_bx[rank][1] = y1;
        s_bx[rank][2] = x2; s_bx[rank][3] = y2;
        s_area[rank] = fmaxf(x2 - x1, 0.0f) * fmaxf(y2 - y1, 0.0f);
        s_keep[rank] = 1;
    }
    __syncthreads();

    // Phase C: greedy NMS — sequential over i, parallel over j.
    for (int i = 0; i < K; i++) {
        __syncthreads();
        if (s_keep[i]) {   // uniform branch (LDS broadcast)
            float bx1 = s_bx[i][0], by1 = s_bx[i][1];
            float bx2 = s_bx[i][2], by2 = s_bx[i][3];
            float ai  = s_area[i];
            for (int j = i + 1 + tid; j < K; j += blockDim.x) {
                if (s_keep[j]) {
                    float xx1 = fmaxf(bx1, s_bx[j][0]);
                    float yy1 = fmaxf(by1, s_bx[j][1]);
                    float xx2 = fminf(bx2, s_bx[j][2]);
                    float yy2 = fminf(by2, s_bx[j][3]);
                    float inter = fmaxf(xx2 - xx1, 0.0f) * fmaxf(yy2 - yy1, 0.0f);
                    float iou = inter / (ai + s_area[j] - inter + 1e-9f);
                    if (iou > NMS_T) s_keep[j] = 0;
                }
            }
        }
    }
    __syncthreads();

    // Phase D: emit kept boxes (sorted order) + full kept count.
    if (tid == 0) {
        float* dst = ws_boxes + (size_t)task * C * 5;
        int kept = 0;
        float cid = (float)c;
        for (int i = 0; i < K; i++) {
            if (s_keep[i]) {
                if (kept < C) {   // only first num_pad(=C) per class can ever land in out
                    dst[kept * 5 + 0] = s_bx[i][0];
                    dst[kept * 5 + 1] = s_bx[i][1];
                    dst[kept * 5 + 2] = s_bx[i][2];
                    dst[kept * 5 + 3] = s_bx[i][3];
                    dst[kept * 5 + 4] = cid;
                }
                kept++;
            }
        }
        ws_counts[task] = kept;
    }
}

// One block per image: class-major prefix sum, pack first num_pad dets, zero tail.
__global__ __launch_bounds__(256) void pack_kernel(
    const float* __restrict__ ws_boxes, const int* __restrict__ ws_counts,
    float* __restrict__ gt, float* __restrict__ nout, int B, int C)
{
    const int b = blockIdx.x;
    const int tid = threadIdx.x;
    const int NC = C - 1;
    const int P = C;              // num_pad == num_classes
    __shared__ int s_off[256];
    __shared__ int s_total;

    if (tid == 0) {
        int acc = 0;
        for (int c = 0; c < NC; c++) { s_off[c] = acc; acc += ws_counts[b * NC + c]; }
        s_total = acc;
    }
    __syncthreads();
    const int n = (s_total < P) ? s_total : P;

    // zero the whole gt slab for this image (d_out is poisoned each run)
    for (int i = tid; i < P * 5; i += blockDim.x)
        gt[(size_t)b * P * 5 + i] = 0.0f;
    __syncthreads();

    for (int idx = tid; idx < NC * P; idx += blockDim.x) {
        int c = idx / P, k = idx % P;
        int cnt = ws_counts[b * NC + c]; if (cnt > P) cnt = P;
        if (k < cnt) {
            int pos = s_off[c] + k;
            if (pos < P) {
                const float* src = ws_boxes + (((size_t)(b * NC + c)) * P + k) * 5;
                float* d = gt + ((size_t)b * P + pos) * 5;
                d[0] = src[0]; d[1] = src[1]; d[2] = src[2]; d[3] = src[3]; d[4] = src[4];
            }
        }
    }
    if (tid == 0) nout[b] = (float)n;
}

extern "C" void kernel_launch(void* const* d_in, const int* in_sizes, int n_in,
                              void* d_out, int out_size, void* d_ws, size_t ws_size,
                              hipStream_t stream) {
    const float* cls_prob  = (const float*)d_in[0];
    const float* rois      = (const float*)d_in[1];
    const float* bbox_pred = (const float*)d_in[2];
    const float* im_info   = (const float*)d_in[3];
    const float* thr       = (const float*)d_in[4];

    const int B = in_sizes[3] / 3;          // im_info is (B,3)
    const int C = in_sizes[4];              // per_class_threshold is (C,)
    const int R = in_sizes[0] / (B * C);    // cls_prob is (B,R,C)
    const int NC = C - 1;

    // workspace: boxes (B*NC tasks x C slots x 5 floats), then counts (B*NC ints)
    float* ws_boxes = (float*)d_ws;
    int*   ws_counts = (int*)(ws_boxes + (size_t)B * NC * C * 5);

    float* gt   = (float*)d_out;                       // (B, C, 5)
    float* nout = (float*)d_out + (size_t)B * C * 5;   // (B,)

    nms_class_kernel<<<B * NC, 256, 0, stream>>>(
        cls_prob, rois, bbox_pred, im_info, thr, ws_boxes, ws_counts, B, R, C);
    pack_kernel<<<B, 256, 0, stream>>>(ws_boxes, ws_counts, gt, nout, B, C);
}

// Round 2
// 99.240 us; speedup vs baseline: 1.0123x; 1.0123x over previous
//
#include <hip/hip_runtime.h>
#include <math.h>

#define MAXC 1024
#define NMS_T 0.3f

// One WAVE (64 threads) per (image, class>=1) task. All cross-lane sync is
// intra-wave (ballot / LDS-broadcast); __syncthreads on a 1-wave block is
// nearly free and only enforces LDS ordering.
__global__ __launch_bounds__(64) void nms_class_kernel(
    const float* __restrict__ cls_prob, const float* __restrict__ rois,
    const float* __restrict__ bbox_pred, const float* __restrict__ im_info,
    const float* __restrict__ thr, float* __restrict__ ws_boxes,
    int* __restrict__ ws_counts, int B, int R, int C)
{
    const int task = blockIdx.x;
    const int NC = C - 1;
    const int b = task / NC;
    const int c = 1 + (task % NC);
    const int tid = threadIdx.x;          // lane 0..63
    const unsigned long long lane_lt = (1ull << tid) - 1ull;

    __shared__ float  s_sc[MAXC];   // compacted scores (roi order)
    __shared__ int    s_ri[MAXC];   // compacted roi indices
    __shared__ float4 s_bx[MAXC];   // boxes in SORTED order
    __shared__ float  s_area[MAXC]; // areas in sorted order
    __shared__ int    s_keep[MAXC]; // only used on cold path (K>256)

    // ---- Phase A: compact valid candidates via ballot prefix (no atomics) ----
    const float tc = thr[c];
    int base = 0;
    for (int r0 = 0; r0 < R; r0 += 64 * 16) {
        float v[16];
#pragma unroll
        for (int k = 0; k < 16; k++) {
            int r = r0 + k * 64 + tid;
            v[k] = (r < R) ? cls_prob[((size_t)b * R + r) * C + c] : -1.0f;
        }
#pragma unroll
        for (int k = 0; k < 16; k++) {
            int r = r0 + k * 64 + tid;
            bool valid = v[k] > tc;
            unsigned long long m = __ballot(valid);
            if (valid) {
                int pos = base + __popcll(m & lane_lt);
                if (pos < MAXC) { s_sc[pos] = v[k]; s_ri[pos] = r; }
            }
            base += __popcll(m);
        }
    }
    int K = (base < MAXC) ? base : MAXC;
    __syncthreads();

    const float maxx = im_info[b * 3 + 1] - 1.0f;
    const float maxy = im_info[b * 3 + 0] - 1.0f;

    // ---- Phase B: rank (score desc, roi asc) == stable argsort(-s);
    //      decode+clip directly into sorted slot ----
    for (int cand = tid; cand < K; cand += 64) {
        const float si = s_sc[cand];
        const int   ri = s_ri[cand];
        int rank = 0;
        for (int j = 0; j < K; j++) {              // uniform j -> LDS broadcast
            float sj = s_sc[j]; int rj = s_ri[j];
            rank += (sj > si) || (sj == si && rj < ri);
        }
        const float* rp = rois + ((size_t)b * R + ri) * 5;
        float rx1 = rp[1], ry1 = rp[2], rx2 = rp[3], ry2 = rp[4];
        float w  = rx2 - rx1 + 1.0f;
        float h  = ry2 - ry1 + 1.0f;
        float cx = rx1 + 0.5f * w;
        float cy = ry1 + 0.5f * h;
        const float* dp = bbox_pred + (((size_t)b * R + ri) * C + c) * 4;
        float d0 = dp[0] * 0.1f, d1 = dp[1] * 0.1f;
        float d2 = dp[2] * 0.2f, d3 = dp[3] * 0.2f;
        float pcx = d0 * w + cx;
        float pcy = d1 * h + cy;
        float pw  = expf(d2) * w;
        float ph  = expf(d3) * h;
        float x1 = fminf(fmaxf(pcx - 0.5f * pw, 0.0f), maxx);
        float x2 = fminf(fmaxf(pcx + 0.5f * pw, 0.0f), maxx);
        float y1 = fminf(fmaxf(pcy - 0.5f * ph, 0.0f), maxy);
        float y2 = fminf(fmaxf(pcy + 0.5f * ph, 0.0f), maxy);
        s_bx[rank] = make_float4(x1, y1, x2, y2);
        s_area[rank] = fmaxf(x2 - x1, 0.0f) * fmaxf(y2 - y1, 0.0f);
    }
    __syncthreads();

    float* dst = ws_boxes + (size_t)task * C * 5;
    const float cid = (float)c;
    const int nchunk = (K + 63) >> 6;

    if (nchunk <= 4) {
        // ---- Phase C fast path: candidates in registers, keep-state in
        //      wave-uniform 64-bit masks, zero barriers ----
        float jx1[4], jy1[4], jx2[4], jy2[4], jar[4];
        unsigned long long km[4];
#pragma unroll
        for (int q = 0; q < 4; q++) {
            int idx = q * 64 + tid;
            float4 bj = (idx < K) ? s_bx[idx] : make_float4(0.f, 0.f, 0.f, 0.f);
            jx1[q] = bj.x; jy1[q] = bj.y; jx2[q] = bj.z; jy2[q] = bj.w;
            jar[q] = (idx < K) ? s_area[idx] : 0.0f;
            int rem = K - q * 64;
            km[q] = (rem >= 64) ? ~0ull : ((rem > 0) ? ((1ull << rem) - 1ull) : 0ull);
        }
        for (int i = 0; i < K; i++) {
            int ci = i >> 6, li = i & 63;
            unsigned long long kw = (ci == 0) ? km[0] : (ci == 1) ? km[1]
                                   : (ci == 2) ? km[2] : km[3];
            if ((kw >> li) & 1ull) {                  // uniform branch
                float4 bi = s_bx[i];                  // LDS broadcast
                float ai = s_area[i];
#pragma unroll
                for (int q = 0; q < 4; q++) {
                    int j = q * 64 + tid;
                    float xx1 = fmaxf(bi.x, jx1[q]);
                    float yy1 = fmaxf(bi.y, jy1[q]);
                    float xx2 = fminf(bi.z, jx2[q]);
                    float yy2 = fminf(bi.w, jy2[q]);
                    float inter = fmaxf(xx2 - xx1, 0.0f) * fmaxf(yy2 - yy1, 0.0f);
                    float iou = inter / (ai + jar[q] - inter + 1e-9f);
                    bool sup = (j < K) && (j > i) && (iou > NMS_T);
                    km[q] &= ~__ballot(sup);
                }
            }
        }
        // ---- Phase D fast path: parallel ballot-prefix emission ----
        int pc[4];
#pragma unroll
        for (int q = 0; q < 4; q++) pc[q] = __popcll(km[q]);
        int total = pc[0] + pc[1] + pc[2] + pc[3];
        int chunk_base = 0;
#pragma unroll
        for (int q = 0; q < 4; q++) {
            int j = q * 64 + tid;
            if (j < K && ((km[q] >> tid) & 1ull)) {
                int pos = chunk_base + __popcll(km[q] & lane_lt);
                if (pos < C) {
                    dst[pos * 5 + 0] = jx1[q];
                    dst[pos * 5 + 1] = jy1[q];
                    dst[pos * 5 + 2] = jx2[q];
                    dst[pos * 5 + 3] = jy2[q];
                    dst[pos * 5 + 4] = cid;
                }
            }
            chunk_base += pc[q];
        }
        if (tid == 0) ws_counts[task] = total;
    } else {
        // ---- Cold path (K > 256): LDS keep flags, wave-serial greedy ----
        for (int i = tid; i < K; i += 64) s_keep[i] = 1;
        __syncthreads();
        for (int i = 0; i < K; i++) {
            if (s_keep[i]) {
                float4 bi = s_bx[i];
                float ai = s_area[i];
                for (int j = i + 1 + tid; j < K; j += 64) {
                    if (s_keep[j]) {
                        float xx1 = fmaxf(bi.x, s_bx[j].x);
                        float yy1 = fmaxf(bi.y, s_bx[j].y);
                        float xx2 = fminf(bi.z, s_bx[j].z);
                        float yy2 = fminf(bi.w, s_bx[j].w);
                        float inter = fmaxf(xx2 - xx1, 0.0f) * fmaxf(yy2 - yy1, 0.0f);
                        float iou = inter / (ai + s_area[j] - inter + 1e-9f);
                        if (iou > NMS_T) s_keep[j] = 0;
                    }
                }
            }
            __syncthreads();
        }
        if (tid == 0) {
            int kept = 0;
            for (int i = 0; i < K; i++) {
                if (s_keep[i]) {
                    if (kept < C) {
                        float4 bv = s_bx[i];
                        dst[kept * 5 + 0] = bv.x;
                        dst[kept * 5 + 1] = bv.y;
                        dst[kept * 5 + 2] = bv.z;
                        dst[kept * 5 + 3] = bv.w;
                        dst[kept * 5 + 4] = cid;
                    }
                    kept++;
                }
            }
            ws_counts[task] = kept;
        }
    }
}

// One block per image: parallel class-major prefix sum, pack first num_pad
// dets, zero tail.
__global__ __launch_bounds__(256) void pack_kernel(
    const float* __restrict__ ws_boxes, const int* __restrict__ ws_counts,
    float* __restrict__ gt, float* __restrict__ nout, int B, int C)
{
    const int b = blockIdx.x;
    const int tid = threadIdx.x;
    const int NC = C - 1;
    const int P = C;                 // num_pad == num_classes
    __shared__ int s_cnt[256];
    __shared__ int s_off[256];
    __shared__ int s_total;

    if (tid < NC) s_cnt[tid] = ws_counts[b * NC + tid];
    __syncthreads();
    if (tid < NC) {
        int acc = 0;
        for (int cc = 0; cc < NC; cc++) {       // uniform cc -> LDS broadcast
            int v = s_cnt[cc];
            if (cc < tid) acc += v;
        }
        s_off[tid] = acc;
        if (tid == NC - 1) s_total = acc + s_cnt[tid];
    }
    __syncthreads();
    const int n = (s_total < P) ? s_total : P;

    // zero the whole gt slab for this image (d_out is poisoned each run)
    for (int i = tid; i < P * 5; i += blockDim.x)
        gt[(size_t)b * P * 5 + i] = 0.0f;
    __syncthreads();

    for (int idx = tid; idx < NC * P; idx += blockDim.x) {
        int c = idx / P, k = idx - c * P;
        int cnt = s_cnt[c]; if (cnt > P) cnt = P;
        if (k < cnt) {
            int pos = s_off[c] + k;
            if (pos < P) {
                const float* src = ws_boxes + (((size_t)(b * NC + c)) * P + k) * 5;
                float* d = gt + ((size_t)b * P + pos) * 5;
                d[0] = src[0]; d[1] = src[1]; d[2] = src[2]; d[3] = src[3]; d[4] = src[4];
            }
        }
    }
    if (tid == 0) nout[b] = (float)n;
}

extern "C" void kernel_launch(void* const* d_in, const int* in_sizes, int n_in,
                              void* d_out, int out_size, void* d_ws, size_t ws_size,
                              hipStream_t stream) {
    const float* cls_prob  = (const float*)d_in[0];
    const float* rois      = (const float*)d_in[1];
    const float* bbox_pred = (const float*)d_in[2];
    const float* im_info   = (const float*)d_in[3];
    const float* thr       = (const float*)d_in[4];

    const int B = in_sizes[3] / 3;          // im_info is (B,3)
    const int C = in_sizes[4];              // per_class_threshold is (C,)
    const int R = in_sizes[0] / (B * C);    // cls_prob is (B,R,C)
    const int NC = C - 1;

    float* ws_boxes = (float*)d_ws;
    int*   ws_counts = (int*)(ws_boxes + (size_t)B * NC * C * 5);

    float* gt   = (float*)d_out;                       // (B, P, 5), P == C
    float* nout = (float*)d_out + (size_t)B * C * 5;   // (B,)

    nms_class_kernel<<<B * NC, 64, 0, stream>>>(
        cls_prob, rois, bbox_pred, im_info, thr, ws_boxes, ws_counts, B, R, C);
    pack_kernel<<<B, 256, 0, stream>>>(ws_boxes, ws_counts, gt, nout, B, C);
}